// Round 2
// baseline (194.047 us; speedup 1.0000x reference)
//
#include <hip/hip_runtime.h>
#include <hip/hip_bf16.h>

// Problem constants (fixed by the bench): B=2, Tq=Tv=2048, D=512, H=8, dh=64.
// Inputs and output are FLOAT32 (reference uses jnp.float32 end-to-end).
#define BATCH 2
#define TSEQ  2048
#define DMODEL 512
#define NHEAD 8
#define DHEAD 64

typedef __bf16 bf16x8 __attribute__((ext_vector_type(8)));
typedef float  f32x4  __attribute__((ext_vector_type(4)));

__device__ __forceinline__ bf16x8 load_b8(const void* p) {
  return __builtin_bit_cast(bf16x8, *reinterpret_cast<const uint4*>(p));
}

// load 8 fp32 and convert to bf16x8 (p must be 16B-aligned)
__device__ __forceinline__ bf16x8 cvt8(const float* p) {
  float4 a = *reinterpret_cast<const float4*>(p);
  float4 b = *reinterpret_cast<const float4*>(p + 4);
  bf16x8 r;
  r[0] = (__bf16)a.x; r[1] = (__bf16)a.y; r[2] = (__bf16)a.z; r[3] = (__bf16)a.w;
  r[4] = (__bf16)b.x; r[5] = (__bf16)b.y; r[6] = (__bf16)b.z; r[7] = (__bf16)b.w;
  return r;
}

// ---------------------------------------------------------------------------
// Kernel 1: K[b][t][o] = sum_d V[b][t][d] * W[o][d] + bias[o]   (conv1d, k=1)
// fp32 in -> bf16 K out. grid 64 blocks (B * Tv/64), 256 threads.
// ---------------------------------------------------------------------------
__global__ __launch_bounds__(256, 1) void conv_kernel(
    const float* __restrict__ V,
    const float* __restrict__ W,
    const float* __restrict__ bias,
    __hip_bfloat16* __restrict__ K) {
  const int bx = blockIdx.x;
  const int b  = bx >> 5;          // 32 blocks per batch
  const int tb = bx & 31;
  const int w  = threadIdx.x >> 6;
  const int l  = threadIdx.x & 63;
  const int lm = l & 15;
  const int lg = l >> 4;
  const int t0 = tb * 64 + w * 16;

  // A-frag: V[t0+lm][ g*32 + lg*8 + j ]
  const float* vrow = V + ((size_t)(b * TSEQ + t0 + lm)) * DHEAD;
  bf16x8 av0 = cvt8(vrow + lg * 8);
  bf16x8 av1 = cvt8(vrow + 32 + lg * 8);

  for (int n = 0; n < 32; ++n) {
    const int o0 = n * 16;
    // B-frag: B[kk=d][n=o] = W[o0+lm][ lg*8 + j ]
    const float* wrow = W + ((size_t)(o0 + lm)) * DHEAD;
    bf16x8 b0 = cvt8(wrow + lg * 8);
    bf16x8 b1 = cvt8(wrow + 32 + lg * 8);
    f32x4 acc = {0.f, 0.f, 0.f, 0.f};
    acc = __builtin_amdgcn_mfma_f32_16x16x32_bf16(av0, b0, acc, 0, 0, 0);
    acc = __builtin_amdgcn_mfma_f32_16x16x32_bf16(av1, b1, acc, 0, 0, 0);
    const float bv = bias[o0 + lm];
    // D: col(o)=lane&15, row(t)=(lane>>4)*4+r
    #pragma unroll
    for (int r = 0; r < 4; ++r) {
      const int t = t0 + lg * 4 + r;
      K[((size_t)(b * TSEQ + t)) * DMODEL + o0 + lm] =
          __float2bfloat16(acc[r] + bv);
    }
  }
}

// ---------------------------------------------------------------------------
// Kernel 2: Vt[b][d][t] = (bf16) V[b][t][d]
// grid 128 blocks (B*64), 256 threads
// ---------------------------------------------------------------------------
__global__ void vt_kernel(const float* __restrict__ V,
                          __hip_bfloat16* __restrict__ Vt) {
  const int bx = blockIdx.x;
  const int b = bx >> 6;
  const int d = bx & 63;
  for (int t = threadIdx.x; t < TSEQ; t += 256) {
    Vt[((size_t)(b * DHEAD + d)) * TSEQ + t] =
        __float2bfloat16(V[((size_t)(b * TSEQ + t)) * DHEAD + d]);
  }
}

// ---------------------------------------------------------------------------
// Kernel 3: fused attention with softmax over HEADS (legacy implicit dim=1).
// grid 256 blocks = B * (Tq/16); 256 threads = 4 waves.
//   S-phase : wave w owns k-slice [w*32, w*32+32); computes S for ALL 8 heads
//             -> softmax over h is lane-local in the D fragment.
//   (LDS)   : normalized weights written bf16 to Ws[h][q][k] (P-transpose).
//   O-phase : wave w owns heads {2w, 2w+1}, consumes all 128 k from Ws.
// ---------------------------------------------------------------------------
__global__ __launch_bounds__(256, 1) void attn_kernel(
    const float* __restrict__ Q,
    const __hip_bfloat16* __restrict__ K,
    const __hip_bfloat16* __restrict__ Vt,
    float* __restrict__ Out) {
  const int bx = blockIdx.x;
  const int b  = bx >> 7;                 // 128 q-blocks per batch
  const int q0 = (bx & 127) << 4;
  const int w  = threadIdx.x >> 6;
  const int l  = threadIdx.x & 63;
  const int lm = l & 15;
  const int lg = l >> 4;

  // k-dim padded 128->136: keeps 16B alignment (136*2B = 17*16B) and rotates
  // bank-quads so ds_read_b128 A-frag reads are ~conflict-free.
  __shared__ __bf16 Ws[NHEAD][16][136];

  // Q A-frags, resident across the whole k-loop: Q[q0+lm][h*64 + g*32 + lg*8..]
  bf16x8 qf[NHEAD][2];
  {
    const float* qrow = Q + ((size_t)(b * TSEQ + q0 + lm)) * DMODEL;
    #pragma unroll
    for (int h = 0; h < NHEAD; ++h) {
      qf[h][0] = cvt8(qrow + h * DHEAD + lg * 8);
      qf[h][1] = cvt8(qrow + h * DHEAD + 32 + lg * 8);
    }
  }

  f32x4 accO[2][4];   // [head within wave-pair][d-tile]
  #pragma unroll
  for (int i = 0; i < 2; ++i)
    #pragma unroll
    for (int j = 0; j < 4; ++j) accO[i][j] = (f32x4){0.f, 0.f, 0.f, 0.f};

  const float scale = 0.125f;             // dh^-0.5

  for (int it = 0; it < TSEQ / 128; ++it) {
    const int kglob = it << 7;

    // ---- S phase ----
    f32x4 s[2][NHEAD];
    #pragma unroll
    for (int ks = 0; ks < 2; ++ks) {
      const int kbase = kglob + w * 32 + ks * 16;
      const __hip_bfloat16* krow = K + ((size_t)(b * TSEQ + kbase + lm)) * DMODEL;
      #pragma unroll
      for (int h = 0; h < NHEAD; ++h) {
        bf16x8 k0 = load_b8(krow + h * DHEAD + lg * 8);
        bf16x8 k1 = load_b8(krow + h * DHEAD + 32 + lg * 8);
        f32x4 acc = {0.f, 0.f, 0.f, 0.f};
        acc = __builtin_amdgcn_mfma_f32_16x16x32_bf16(qf[h][0], k0, acc, 0, 0, 0);
        acc = __builtin_amdgcn_mfma_f32_16x16x32_bf16(qf[h][1], k1, acc, 0, 0, 0);
        s[ks][h] = acc;
      }
    }

    // ---- softmax over heads (lane-local) + write W to LDS ----
    #pragma unroll
    for (int ks = 0; ks < 2; ++ks) {
      const int kl = w * 32 + ks * 16 + lm;
      #pragma unroll
      for (int r = 0; r < 4; ++r) {
        float v[NHEAD];
        #pragma unroll
        for (int h = 0; h < NHEAD; ++h) v[h] = s[ks][h][r] * scale;
        float m = v[0];
        #pragma unroll
        for (int h = 1; h < NHEAD; ++h) m = fmaxf(m, v[h]);
        float sum = 0.f;
        #pragma unroll
        for (int h = 0; h < NHEAD; ++h) { v[h] = __expf(v[h] - m); sum += v[h]; }
        const float inv = __builtin_amdgcn_rcpf(sum);
        const int qrw = lg * 4 + r;
        #pragma unroll
        for (int h = 0; h < NHEAD; ++h)
          Ws[h][qrw][kl] = (__bf16)(v[h] * inv);
      }
    }
    __syncthreads();

    // ---- O phase: wave owns heads {2w, 2w+1}, all 128 k of this iter ----
    const int h0 = w * 2;
    #pragma unroll
    for (int ksub = 0; ksub < 4; ++ksub) {
      bf16x8 a0 = load_b8(&Ws[h0][lm][ksub * 32 + lg * 8]);
      bf16x8 a1 = load_b8(&Ws[h0 + 1][lm][ksub * 32 + lg * 8]);
      #pragma unroll
      for (int dt = 0; dt < 4; ++dt) {
        bf16x8 bv = load_b8(Vt + ((size_t)(b * DHEAD + dt * 16 + lm)) * TSEQ +
                            kglob + ksub * 32 + lg * 8);
        accO[0][dt] = __builtin_amdgcn_mfma_f32_16x16x32_bf16(a0, bv, accO[0][dt], 0, 0, 0);
        accO[1][dt] = __builtin_amdgcn_mfma_f32_16x16x32_bf16(a1, bv, accO[1][dt], 0, 0, 0);
      }
    }
    __syncthreads();
  }

  // ---- epilogue: Out[b][q][ (2w+h2)*64 + dt*16 + lm ] (fp32) ----
  #pragma unroll
  for (int h2 = 0; h2 < 2; ++h2) {
    #pragma unroll
    for (int dt = 0; dt < 4; ++dt) {
      #pragma unroll
      for (int r = 0; r < 4; ++r) {
        const int q = q0 + lg * 4 + r;
        const int d = (w * 2 + h2) * DHEAD + dt * 16 + lm;
        Out[((size_t)(b * TSEQ + q)) * DMODEL + d] = accO[h2][dt][r];
      }
    }
  }
}

// ---------------------------------------------------------------------------
extern "C" void kernel_launch(void* const* d_in, const int* in_sizes, int n_in,
                              void* d_out, int out_size, void* d_ws, size_t ws_size,
                              hipStream_t stream) {
  const float* Q    = (const float*)d_in[0];
  const float* V    = (const float*)d_in[1];
  const float* W    = (const float*)d_in[2];
  const float* bias = (const float*)d_in[3];
  float* Out = (float*)d_out;

  // ws layout: K bf16 [2][2048][512] (4 MiB) | Vt bf16 [2][64][2048] (0.5 MiB)
  __hip_bfloat16* Kbuf = (__hip_bfloat16*)d_ws;
  __hip_bfloat16* Vt   = Kbuf + (size_t)BATCH * TSEQ * DMODEL;

  conv_kernel<<<64, 256, 0, stream>>>(V, W, bias, Kbuf);
  vt_kernel<<<128, 256, 0, stream>>>(V, Vt);
  attn_kernel<<<256, 256, 0, stream>>>(Q, Kbuf, Vt, Out);
}

// Round 4
// 175.318 us; speedup vs baseline: 1.1068x; 1.1068x over previous
//
#include <hip/hip_runtime.h>
#include <hip/hip_bf16.h>

// Problem constants (fixed by the bench): B=2, Tq=Tv=2048, D=512, H=8, dh=64.
// Inputs and output are FLOAT32.
#define BATCH 2
#define TSEQ  2048
#define DMODEL 512
#define NHEAD 8
#define DHEAD 64
#define KCHUNKS 4          // k-split factor: grid = B*128*KCHUNKS blocks

typedef __bf16 bf16x2 __attribute__((ext_vector_type(2)));
typedef __bf16 bf16x8 __attribute__((ext_vector_type(8)));
typedef float  f32x4  __attribute__((ext_vector_type(4)));

__device__ __forceinline__ bf16x8 load_b8(const void* p) {
  return __builtin_bit_cast(bf16x8, *reinterpret_cast<const uint4*>(p));
}

// load 8 fp32 and convert to bf16x8 (p must be 16B-aligned)
__device__ __forceinline__ bf16x8 cvt8(const float* p) {
  float4 a = *reinterpret_cast<const float4*>(p);
  float4 b = *reinterpret_cast<const float4*>(p + 4);
  bf16x8 r;
  r[0] = (__bf16)a.x; r[1] = (__bf16)a.y; r[2] = (__bf16)a.z; r[3] = (__bf16)a.w;
  r[4] = (__bf16)b.x; r[5] = (__bf16)b.y; r[6] = (__bf16)b.z; r[7] = (__bf16)b.w;
  return r;
}

// ---------------------------------------------------------------------------
// Kernel 0: zero the fp32 output (attn accumulates into it atomically).
// 2M floats = 512K float4; 2048 blocks x 256 threads.
// ---------------------------------------------------------------------------
__global__ void zero_kernel(float4* __restrict__ p) {
  p[blockIdx.x * 256 + threadIdx.x] = float4{0.f, 0.f, 0.f, 0.f};
}

// ---------------------------------------------------------------------------
// Kernel 1: K[b][t][o] = sum_d V[b][t][d] * W[o][d] + bias[o]   (conv1d, k=1)
// grid 256 blocks (B * Tv/16), 256 threads; wave w owns 8 of 32 o-tiles.
// ---------------------------------------------------------------------------
__global__ __launch_bounds__(256) void conv_kernel(
    const float* __restrict__ V,
    const float* __restrict__ W,
    const float* __restrict__ bias,
    __hip_bfloat16* __restrict__ K) {
  const int bx = blockIdx.x;
  const int b  = bx >> 7;
  const int t0 = (bx & 127) << 4;
  const int w  = threadIdx.x >> 6;
  const int l  = threadIdx.x & 63;
  const int lm = l & 15;
  const int lg = l >> 4;

  const float* vrow = V + ((size_t)(b * TSEQ + t0 + lm)) * DHEAD;
  bf16x8 av0 = cvt8(vrow + lg * 8);
  bf16x8 av1 = cvt8(vrow + 32 + lg * 8);

  #pragma unroll
  for (int n = 0; n < 8; ++n) {
    const int o0 = (w * 8 + n) * 16;
    const float* wrow = W + ((size_t)(o0 + lm)) * DHEAD;
    bf16x8 b0 = cvt8(wrow + lg * 8);
    bf16x8 b1 = cvt8(wrow + 32 + lg * 8);
    f32x4 acc = {0.f, 0.f, 0.f, 0.f};
    acc = __builtin_amdgcn_mfma_f32_16x16x32_bf16(av0, b0, acc, 0, 0, 0);
    acc = __builtin_amdgcn_mfma_f32_16x16x32_bf16(av1, b1, acc, 0, 0, 0);
    const float bv = bias[o0 + lm];
    #pragma unroll
    for (int r = 0; r < 4; ++r) {
      const int t = t0 + lg * 4 + r;
      K[((size_t)(b * TSEQ + t)) * DMODEL + o0 + lm] =
          __float2bfloat16(acc[r] + bv);
    }
  }
}

// ---------------------------------------------------------------------------
// Kernel 2: Vt[b][d][t] = (bf16) V[b][t][d] via LDS tile transpose.
// grid 64 blocks (B * Tv/64), 256 threads; coalesced reads AND writes.
// ---------------------------------------------------------------------------
__global__ __launch_bounds__(256) void vt_kernel(const float* __restrict__ V,
                                                 __hip_bfloat16* __restrict__ Vt) {
  const int bx = blockIdx.x;
  const int b  = bx >> 5;
  const int t0 = (bx & 31) << 6;
  const int tid = threadIdx.x;
  __shared__ float tile[64][65];

  #pragma unroll
  for (int p = 0; p < 4; ++p) {
    const int r = p * 16 + (tid >> 4);
    const int c = (tid & 15) * 4;
    float4 v = *reinterpret_cast<const float4*>(
        &V[((size_t)(b * TSEQ + t0 + r)) * DHEAD + c]);
    tile[r][c]     = v.x;
    tile[r][c + 1] = v.y;
    tile[r][c + 2] = v.z;
    tile[r][c + 3] = v.w;
  }
  __syncthreads();

  // each thread writes 16 bf16 (32B) of one Vt row
  const int d  = tid >> 2;
  const int ts = (tid & 3) * 16;
  uint u[8];
  #pragma unroll
  for (int j = 0; j < 8; ++j) {
    bf16x2 p2;
    p2[0] = (__bf16)tile[ts + 2 * j][d];
    p2[1] = (__bf16)tile[ts + 2 * j + 1][d];
    u[j] = __builtin_bit_cast(uint, p2);
  }
  uint4* dst = reinterpret_cast<uint4*>(
      Vt + ((size_t)(b * DHEAD + d)) * TSEQ + t0 + ts);
  dst[0] = uint4{u[0], u[1], u[2], u[3]};
  dst[1] = uint4{u[4], u[5], u[6], u[7]};
}

// ---------------------------------------------------------------------------
// Kernel 3: fused attention, softmax over HEADS (lane-local).
// grid = B * (Tq/16) * KCHUNKS = 1024 blocks; 256 threads = 4 waves.
// Each block handles k in [c*512, c*512+512) and atomically accumulates O.
// ---------------------------------------------------------------------------
__global__ __launch_bounds__(256, 4) void attn_kernel(
    const float* __restrict__ Q,
    const __hip_bfloat16* __restrict__ K,
    const __hip_bfloat16* __restrict__ Vt,
    float* __restrict__ Out) {
  const int bx = blockIdx.x;
  const int c  = bx & (KCHUNKS - 1);
  const int q0 = ((bx >> 2) & 127) << 4;
  const int b  = bx >> 9;
  const int w  = threadIdx.x >> 6;
  const int l  = threadIdx.x & 63;
  const int lm = l & 15;
  const int lg = l >> 4;

  // k-dim padded 128->136: keeps 16B alignment (272B = 17*16B), rotates banks.
  __shared__ __bf16 Ws[NHEAD][16][136];

  bf16x8 qf[NHEAD][2];
  {
    const float* qrow = Q + ((size_t)(b * TSEQ + q0 + lm)) * DMODEL;
    #pragma unroll
    for (int h = 0; h < NHEAD; ++h) {
      qf[h][0] = cvt8(qrow + h * DHEAD + lg * 8);
      qf[h][1] = cvt8(qrow + h * DHEAD + 32 + lg * 8);
    }
  }

  f32x4 accO[2][4];
  #pragma unroll
  for (int i = 0; i < 2; ++i)
    #pragma unroll
    for (int j = 0; j < 4; ++j) accO[i][j] = (f32x4){0.f, 0.f, 0.f, 0.f};

  const float scale = 0.125f;

  for (int it = 0; it < 512 / 128; ++it) {
    const int kglob = c * 512 + (it << 7);

    // ---- S phase: wave w owns k-slice [w*32, w*32+32), all 8 heads ----
    f32x4 s[2][NHEAD];
    #pragma unroll
    for (int ks = 0; ks < 2; ++ks) {
      const int kbase = kglob + w * 32 + ks * 16;
      const __hip_bfloat16* krow = K + ((size_t)(b * TSEQ + kbase + lm)) * DMODEL;
      #pragma unroll
      for (int h = 0; h < NHEAD; ++h) {
        bf16x8 k0 = load_b8(krow + h * DHEAD + lg * 8);
        bf16x8 k1 = load_b8(krow + h * DHEAD + 32 + lg * 8);
        f32x4 acc = {0.f, 0.f, 0.f, 0.f};
        acc = __builtin_amdgcn_mfma_f32_16x16x32_bf16(qf[h][0], k0, acc, 0, 0, 0);
        acc = __builtin_amdgcn_mfma_f32_16x16x32_bf16(qf[h][1], k1, acc, 0, 0, 0);
        s[ks][h] = acc;
      }
    }

    // ---- softmax over heads (lane-local) + transpose to LDS ----
    #pragma unroll
    for (int ks = 0; ks < 2; ++ks) {
      const int kl = w * 32 + ks * 16 + lm;
      #pragma unroll
      for (int r = 0; r < 4; ++r) {
        float v[NHEAD];
        #pragma unroll
        for (int h = 0; h < NHEAD; ++h) v[h] = s[ks][h][r] * scale;
        float m = v[0];
        #pragma unroll
        for (int h = 1; h < NHEAD; ++h) m = fmaxf(m, v[h]);
        float sum = 0.f;
        #pragma unroll
        for (int h = 0; h < NHEAD; ++h) { v[h] = __expf(v[h] - m); sum += v[h]; }
        const float inv = __builtin_amdgcn_rcpf(sum);
        const int qrw = lg * 4 + r;
        #pragma unroll
        for (int h = 0; h < NHEAD; ++h)
          Ws[h][qrw][kl] = (__bf16)(v[h] * inv);
      }
    }
    __syncthreads();

    // ---- O phase: wave owns heads {2w, 2w+1}, all 128 k of this iter ----
    const int h0 = w * 2;
    #pragma unroll
    for (int ksub = 0; ksub < 4; ++ksub) {
      bf16x8 a0 = load_b8(&Ws[h0][lm][ksub * 32 + lg * 8]);
      bf16x8 a1 = load_b8(&Ws[h0 + 1][lm][ksub * 32 + lg * 8]);
      #pragma unroll
      for (int dt = 0; dt < 4; ++dt) {
        bf16x8 bv = load_b8(Vt + ((size_t)(b * DHEAD + dt * 16 + lm)) * TSEQ +
                            kglob + ksub * 32 + lg * 8);
        accO[0][dt] = __builtin_amdgcn_mfma_f32_16x16x32_bf16(a0, bv, accO[0][dt], 0, 0, 0);
        accO[1][dt] = __builtin_amdgcn_mfma_f32_16x16x32_bf16(a1, bv, accO[1][dt], 0, 0, 0);
      }
    }
    __syncthreads();
  }

  // ---- epilogue: atomic-accumulate into fp32 output ----
  #pragma unroll
  for (int h2 = 0; h2 < 2; ++h2) {
    #pragma unroll
    for (int dt = 0; dt < 4; ++dt) {
      #pragma unroll
      for (int r = 0; r < 4; ++r) {
        const int q = q0 + lg * 4 + r;
        const int d = (w * 2 + h2) * DHEAD + dt * 16 + lm;
        unsafeAtomicAdd(&Out[((size_t)(b * TSEQ + q)) * DMODEL + d],
                        accO[h2][dt][r]);
      }
    }
  }
}

// ---------------------------------------------------------------------------
extern "C" void kernel_launch(void* const* d_in, const int* in_sizes, int n_in,
                              void* d_out, int out_size, void* d_ws, size_t ws_size,
                              hipStream_t stream) {
  const float* Q    = (const float*)d_in[0];
  const float* V    = (const float*)d_in[1];
  const float* W    = (const float*)d_in[2];
  const float* bias = (const float*)d_in[3];
  float* Out = (float*)d_out;

  // ws layout: K bf16 [2][2048][512] (4 MiB) | Vt bf16 [2][64][2048] (0.5 MiB)
  __hip_bfloat16* Kbuf = (__hip_bfloat16*)d_ws;
  __hip_bfloat16* Vt   = Kbuf + (size_t)BATCH * TSEQ * DMODEL;

  zero_kernel<<<2048, 256, 0, stream>>>((float4*)Out);
  conv_kernel<<<256, 256, 0, stream>>>(V, W, bias, Kbuf);
  vt_kernel<<<64, 256, 0, stream>>>(V, Vt);
  attn_kernel<<<BATCH * 128 * KCHUNKS, 256, 0, stream>>>(Q, Kbuf, Vt, Out);
}

// Round 5
// 138.417 us; speedup vs baseline: 1.4019x; 1.2666x over previous
//
#include <hip/hip_runtime.h>
#include <hip/hip_bf16.h>

// Problem constants (fixed by the bench): B=2, Tq=Tv=2048, D=512, H=8, dh=64.
// Inputs and output are FLOAT32.
#define BATCH 2
#define TSEQ  2048
#define DMODEL 512
#define NHEAD 8
#define DHEAD 64

typedef __bf16 bf16x2 __attribute__((ext_vector_type(2)));
typedef __bf16 bf16x4 __attribute__((ext_vector_type(4)));
typedef __bf16 bf16x8 __attribute__((ext_vector_type(8)));
typedef float  f32x4  __attribute__((ext_vector_type(4)));

__device__ __forceinline__ bf16x8 load_b8(const void* p) {
  return __builtin_bit_cast(bf16x8, *reinterpret_cast<const uint4*>(p));
}
__device__ __forceinline__ bf16x4 load_b4(const void* p) {
  return __builtin_bit_cast(bf16x4, *reinterpret_cast<const uint2*>(p));
}

// load 8 fp32 and convert to bf16x8 (p must be 16B-aligned)
__device__ __forceinline__ bf16x8 cvt8(const float* p) {
  float4 a = *reinterpret_cast<const float4*>(p);
  float4 b = *reinterpret_cast<const float4*>(p + 4);
  bf16x8 r;
  r[0] = (__bf16)a.x; r[1] = (__bf16)a.y; r[2] = (__bf16)a.z; r[3] = (__bf16)a.w;
  r[4] = (__bf16)b.x; r[5] = (__bf16)b.y; r[6] = (__bf16)b.z; r[7] = (__bf16)b.w;
  return r;
}

// ---------------------------------------------------------------------------
// Kernel 1: K[b][t][o] = sum_d V[b][t][d] * W[o][d] + bias[o]   (conv1d, k=1)
// grid 256 blocks (B * Tv/16), 256 threads; wave w owns 8 of 32 o-tiles.
// ---------------------------------------------------------------------------
__global__ __launch_bounds__(256) void conv_kernel(
    const float* __restrict__ V,
    const float* __restrict__ W,
    const float* __restrict__ bias,
    __hip_bfloat16* __restrict__ K) {
  const int bx = blockIdx.x;
  const int b  = bx >> 7;
  const int t0 = (bx & 127) << 4;
  const int w  = threadIdx.x >> 6;
  const int l  = threadIdx.x & 63;
  const int lm = l & 15;
  const int lg = l >> 4;

  const float* vrow = V + ((size_t)(b * TSEQ + t0 + lm)) * DHEAD;
  bf16x8 av0 = cvt8(vrow + lg * 8);
  bf16x8 av1 = cvt8(vrow + 32 + lg * 8);

  #pragma unroll
  for (int n = 0; n < 8; ++n) {
    const int o0 = (w * 8 + n) * 16;
    const float* wrow = W + ((size_t)(o0 + lm)) * DHEAD;
    bf16x8 b0 = cvt8(wrow + lg * 8);
    bf16x8 b1 = cvt8(wrow + 32 + lg * 8);
    f32x4 acc = {0.f, 0.f, 0.f, 0.f};
    acc = __builtin_amdgcn_mfma_f32_16x16x32_bf16(av0, b0, acc, 0, 0, 0);
    acc = __builtin_amdgcn_mfma_f32_16x16x32_bf16(av1, b1, acc, 0, 0, 0);
    const float bv = bias[o0 + lm];
    #pragma unroll
    for (int r = 0; r < 4; ++r) {
      const int t = t0 + lg * 4 + r;
      K[((size_t)(b * TSEQ + t)) * DMODEL + o0 + lm] =
          __float2bfloat16(acc[r] + bv);
    }
  }
}

// ---------------------------------------------------------------------------
// Kernel 2: Vt[b][d][t] = (bf16) V[b][t][d] via LDS tile transpose.
// grid 64 blocks (B * Tv/64), 256 threads.
// ---------------------------------------------------------------------------
__global__ __launch_bounds__(256) void vt_kernel(const float* __restrict__ V,
                                                 __hip_bfloat16* __restrict__ Vt) {
  const int bx = blockIdx.x;
  const int b  = bx >> 5;
  const int t0 = (bx & 31) << 6;
  const int tid = threadIdx.x;
  __shared__ float tile[64][65];

  #pragma unroll
  for (int p = 0; p < 4; ++p) {
    const int r = p * 16 + (tid >> 4);
    const int c = (tid & 15) * 4;
    float4 v = *reinterpret_cast<const float4*>(
        &V[((size_t)(b * TSEQ + t0 + r)) * DHEAD + c]);
    tile[r][c]     = v.x;
    tile[r][c + 1] = v.y;
    tile[r][c + 2] = v.z;
    tile[r][c + 3] = v.w;
  }
  __syncthreads();

  const int d  = tid >> 2;
  const int ts = (tid & 3) * 16;
  uint u[8];
  #pragma unroll
  for (int j = 0; j < 8; ++j) {
    bf16x2 p2;
    p2[0] = (__bf16)tile[ts + 2 * j][d];
    p2[1] = (__bf16)tile[ts + 2 * j + 1][d];
    u[j] = __builtin_bit_cast(uint, p2);
  }
  uint4* dst = reinterpret_cast<uint4*>(
      Vt + ((size_t)(b * DHEAD + d)) * TSEQ + t0 + ts);
  dst[0] = uint4{u[0], u[1], u[2], u[3]};
  dst[1] = uint4{u[4], u[5], u[6], u[7]};
}

// ---------------------------------------------------------------------------
// Kernel 3: fused attention, softmax over HEADS (lane-local), barrier-free
// k-loop. grid 256 blocks = B * (Tq/16), 1 block/CU, XCD-swizzled.
// 512 threads = 8 waves; wave w owns k-strip [w*256, w*256+256).
//   S^T via mfma(K_frag, Q_frag): lane holds S[k=(lg*4+r)][q=lm] for 8 heads.
//   softmax over h: lane-local. Normalized weights land EXACTLY in the
//   B-fragment layout for the PV mfma (n=q=lm, kdim=(lg)*4+j) -> no LDS
//   roundtrip, no barriers in the k-loop.
//   O^T[h][d][q] accumulates in registers (128 VGPR); epilogue reduces the
//   8 k-strips via LDS (8 rounds, one per head) and writes fp32 out once.
// ---------------------------------------------------------------------------
__global__ __launch_bounds__(512, 2) void attn_kernel(
    const float* __restrict__ Q,
    const __hip_bfloat16* __restrict__ K,
    const __hip_bfloat16* __restrict__ Vt,
    float* __restrict__ Out) {
  // XCD swizzle: 256 blocks, 8 XCDs -> XCD x gets logical blocks [x*32, x*32+32)
  const int bx = blockIdx.x;
  const int L  = (bx & 7) * 32 + (bx >> 3);
  const int b  = L >> 7;
  const int q0 = (L & 127) << 4;
  const int tid = threadIdx.x;
  const int w  = tid >> 6;
  const int l  = tid & 63;
  const int lm = l & 15;
  const int lg = l >> 4;

  __shared__ __bf16 Qs[16 * 512];      // XOR-swizzled q-tile (16 rows x 1KB)
  __shared__ float  Obuf[8][64][17];   // [wave][d][q+pad] reduction buffer

  // ---- stage Q tile to LDS (bf16, swizzled) ----
  {
    const int row = tid >> 5;          // 0..15
    const int seg = tid & 31;          // 16 floats each
    const float* src = Q + ((size_t)(b * TSEQ + q0 + row)) * DMODEL + seg * 16;
    bf16x8 lo = cvt8(src);
    bf16x8 hi = cvt8(src + 8);
    char* base = (char*)Qs;
    const int sw = (row & 7) << 4;
    *(bf16x8*)(base + ((row * 1024 + seg * 32) ^ sw))      = lo;
    *(bf16x8*)(base + ((row * 1024 + seg * 32 + 16) ^ sw)) = hi;
  }
  __syncthreads();

  f32x4 accO[NHEAD][4];   // [h][dt], O^T: d = dt*16 + lg*4 + r, q = lm
  #pragma unroll
  for (int h = 0; h < NHEAD; ++h)
    #pragma unroll
    for (int j = 0; j < 4; ++j) accO[h][j] = (f32x4){0.f, 0.f, 0.f, 0.f};

  const float cl2 = 0.125f * 1.44269504f;   // dh^-0.5 * log2(e)
  const char* qb = (const char*)Qs;
  const int qsw = (lm & 7) << 4;

  for (int pr = 0; pr < 8; ++pr) {
    const int kset0 = w * 256 + pr * 32;
    bf16x8 wf[NHEAD];                  // normalized weights, B-frag layout

    #pragma unroll
    for (int s2 = 0; s2 < 2; ++s2) {
      const int kset = kset0 + s2 * 16;
      f32x4 sv[NHEAD];
      const __hip_bfloat16* kbase =
          K + ((size_t)(b * TSEQ + kset + lm)) * DMODEL + lg * 8;
      #pragma unroll
      for (int h = 0; h < NHEAD; ++h) {
        bf16x8 kf0 = load_b8(kbase + h * 64);
        bf16x8 kf1 = load_b8(kbase + h * 64 + 32);
        bf16x8 qf0 = *(const bf16x8*)(qb + ((lm * 1024 + h * 128 + lg * 16) ^ qsw));
        bf16x8 qf1 = *(const bf16x8*)(qb + ((lm * 1024 + h * 128 + 64 + lg * 16) ^ qsw));
        f32x4 t = {0.f, 0.f, 0.f, 0.f};
        t = __builtin_amdgcn_mfma_f32_16x16x32_bf16(kf0, qf0, t, 0, 0, 0);
        t = __builtin_amdgcn_mfma_f32_16x16x32_bf16(kf1, qf1, t, 0, 0, 0);
        sv[h] = t;
      }
      // softmax over heads (lane-local), per k-slot r
      #pragma unroll
      for (int r = 0; r < 4; ++r) {
        float v[NHEAD];
        #pragma unroll
        for (int h = 0; h < NHEAD; ++h) v[h] = sv[h][r] * cl2;
        float m = fmaxf(fmaxf(fmaxf(v[0], v[1]), fmaxf(v[2], v[3])),
                        fmaxf(fmaxf(v[4], v[5]), fmaxf(v[6], v[7])));
        float e[NHEAD];
        float sum = 0.f;
        #pragma unroll
        for (int h = 0; h < NHEAD; ++h) { e[h] = exp2f(v[h] - m); sum += e[h]; }
        const float inv = __builtin_amdgcn_rcpf(sum);
        #pragma unroll
        for (int h = 0; h < NHEAD; ++h)
          wf[h][s2 * 4 + r] = (__bf16)(e[h] * inv);
      }
    }

    // ---- PV: O^T[d][q] += sum_k V[k][d] * w[q][k], K=32 over the pair ----
    const __hip_bfloat16* vbase =
        Vt + ((size_t)(b * DHEAD + lm)) * TSEQ + kset0 + lg * 4;
    #pragma unroll
    for (int dt = 0; dt < 4; ++dt) {
      bf16x4 v0 = load_b4(vbase + (size_t)dt * 16 * TSEQ);
      bf16x4 v1 = load_b4(vbase + (size_t)dt * 16 * TSEQ + 16);
      bf16x8 vf;
      #pragma unroll
      for (int j = 0; j < 4; ++j) { vf[j] = v0[j]; vf[j + 4] = v1[j]; }
      #pragma unroll
      for (int h = 0; h < NHEAD; ++h)
        accO[h][dt] = __builtin_amdgcn_mfma_f32_16x16x32_bf16(vf, wf[h], accO[h][dt], 0, 0, 0);
    }
  }

  // ---- epilogue: reduce 8 k-strip waves via LDS, one head per round ----
  #pragma unroll 1
  for (int h = 0; h < NHEAD; ++h) {
    #pragma unroll
    for (int dt = 0; dt < 4; ++dt)
      #pragma unroll
      for (int r = 0; r < 4; ++r)
        Obuf[w][dt * 16 + lg * 4 + r][lm] = accO[h][dt][r];
    __syncthreads();

    {
      const int q  = tid >> 5;         // 0..15
      const int d0 = (tid & 31) * 2;   // 2 d per thread
      float s0 = 0.f, s1 = 0.f;
      #pragma unroll
      for (int ww = 0; ww < 8; ++ww) {
        s0 += Obuf[ww][d0][q];
        s1 += Obuf[ww][d0 + 1][q];
      }
      float2* dst = reinterpret_cast<float2*>(
          &Out[((size_t)(b * TSEQ + q0 + q)) * DMODEL + h * DHEAD + d0]);
      *dst = float2{s0, s1};
    }
    __syncthreads();
  }
}

// ---------------------------------------------------------------------------
extern "C" void kernel_launch(void* const* d_in, const int* in_sizes, int n_in,
                              void* d_out, int out_size, void* d_ws, size_t ws_size,
                              hipStream_t stream) {
  const float* Q    = (const float*)d_in[0];
  const float* V    = (const float*)d_in[1];
  const float* W    = (const float*)d_in[2];
  const float* bias = (const float*)d_in[3];
  float* Out = (float*)d_out;

  // ws layout: K bf16 [2][2048][512] (4 MiB) | Vt bf16 [2][64][2048] (0.5 MiB)
  __hip_bfloat16* Kbuf = (__hip_bfloat16*)d_ws;
  __hip_bfloat16* Vt   = Kbuf + (size_t)BATCH * TSEQ * DMODEL;

  conv_kernel<<<256, 256, 0, stream>>>(V, W, bias, Kbuf);
  vt_kernel<<<64, 256, 0, stream>>>(V, Vt);
  attn_kernel<<<BATCH * (TSEQ / 16), 512, 0, stream>>>(Q, Kbuf, Vt, Out);
}

// Round 6
// 118.900 us; speedup vs baseline: 1.6320x; 1.1641x over previous
//
#include <hip/hip_runtime.h>
#include <hip/hip_bf16.h>

// Problem constants (fixed by the bench): B=2, Tq=Tv=2048, D=512, H=8, dh=64.
// Inputs and output are FLOAT32.
#define BATCH 2
#define TSEQ  2048
#define DMODEL 512
#define NHEAD 8
#define DHEAD 64

typedef __bf16 bf16x2 __attribute__((ext_vector_type(2)));
typedef __bf16 bf16x4 __attribute__((ext_vector_type(4)));
typedef __bf16 bf16x8 __attribute__((ext_vector_type(8)));
typedef float  f32x4  __attribute__((ext_vector_type(4)));

__device__ __forceinline__ bf16x8 load_b8(const void* p) {
  return __builtin_bit_cast(bf16x8, *reinterpret_cast<const uint4*>(p));
}
__device__ __forceinline__ bf16x4 load_b4(const void* p) {
  return __builtin_bit_cast(bf16x4, *reinterpret_cast<const uint2*>(p));
}

// load 8 fp32 and convert to bf16x8 (p must be 16B-aligned)
__device__ __forceinline__ bf16x8 cvt8(const float* p) {
  float4 a = *reinterpret_cast<const float4*>(p);
  float4 b = *reinterpret_cast<const float4*>(p + 4);
  bf16x8 r;
  r[0] = (__bf16)a.x; r[1] = (__bf16)a.y; r[2] = (__bf16)a.z; r[3] = (__bf16)a.w;
  r[4] = (__bf16)b.x; r[5] = (__bf16)b.y; r[6] = (__bf16)b.z; r[7] = (__bf16)b.w;
  return r;
}

// ---------------------------------------------------------------------------
// Kernel 1: K[b][t][o] = sum_d V[b][t][d] * W[o][d] + bias[o]   (conv1d, k=1)
// grid 256 blocks (B * Tv/16), 256 threads; wave w owns 8 of 32 o-tiles.
// ---------------------------------------------------------------------------
__global__ __launch_bounds__(256) void conv_kernel(
    const float* __restrict__ V,
    const float* __restrict__ W,
    const float* __restrict__ bias,
    __hip_bfloat16* __restrict__ K) {
  const int bx = blockIdx.x;
  const int b  = bx >> 7;
  const int t0 = (bx & 127) << 4;
  const int w  = threadIdx.x >> 6;
  const int l  = threadIdx.x & 63;
  const int lm = l & 15;
  const int lg = l >> 4;

  const float* vrow = V + ((size_t)(b * TSEQ + t0 + lm)) * DHEAD;
  bf16x8 av0 = cvt8(vrow + lg * 8);
  bf16x8 av1 = cvt8(vrow + 32 + lg * 8);

  #pragma unroll
  for (int n = 0; n < 8; ++n) {
    const int o0 = (w * 8 + n) * 16;
    const float* wrow = W + ((size_t)(o0 + lm)) * DHEAD;
    bf16x8 b0 = cvt8(wrow + lg * 8);
    bf16x8 b1 = cvt8(wrow + 32 + lg * 8);
    f32x4 acc = {0.f, 0.f, 0.f, 0.f};
    acc = __builtin_amdgcn_mfma_f32_16x16x32_bf16(av0, b0, acc, 0, 0, 0);
    acc = __builtin_amdgcn_mfma_f32_16x16x32_bf16(av1, b1, acc, 0, 0, 0);
    const float bv = bias[o0 + lm];
    #pragma unroll
    for (int r = 0; r < 4; ++r) {
      const int t = t0 + lg * 4 + r;
      K[((size_t)(b * TSEQ + t)) * DMODEL + o0 + lm] =
          __float2bfloat16(acc[r] + bv);
    }
  }
}

// ---------------------------------------------------------------------------
// Kernel 2: Vt[b][d][t] = (bf16) V[b][t][d] via LDS tile transpose.
// grid 64 blocks (B * Tv/64), 256 threads.
// ---------------------------------------------------------------------------
__global__ __launch_bounds__(256) void vt_kernel(const float* __restrict__ V,
                                                 __hip_bfloat16* __restrict__ Vt) {
  const int bx = blockIdx.x;
  const int b  = bx >> 5;
  const int t0 = (bx & 31) << 6;
  const int tid = threadIdx.x;
  __shared__ float tile[64][65];

  #pragma unroll
  for (int p = 0; p < 4; ++p) {
    const int r = p * 16 + (tid >> 4);
    const int c = (tid & 15) * 4;
    float4 v = *reinterpret_cast<const float4*>(
        &V[((size_t)(b * TSEQ + t0 + r)) * DHEAD + c]);
    tile[r][c]     = v.x;
    tile[r][c + 1] = v.y;
    tile[r][c + 2] = v.z;
    tile[r][c + 3] = v.w;
  }
  __syncthreads();

  const int d  = tid >> 2;
  const int ts = (tid & 3) * 16;
  uint u[8];
  #pragma unroll
  for (int j = 0; j < 8; ++j) {
    bf16x2 p2;
    p2[0] = (__bf16)tile[ts + 2 * j][d];
    p2[1] = (__bf16)tile[ts + 2 * j + 1][d];
    u[j] = __builtin_bit_cast(uint, p2);
  }
  uint4* dst = reinterpret_cast<uint4*>(
      Vt + ((size_t)(b * DHEAD + d)) * TSEQ + t0 + ts);
  dst[0] = uint4{u[0], u[1], u[2], u[3]};
  dst[1] = uint4{u[4], u[5], u[6], u[7]};
}

// ---------------------------------------------------------------------------
// Kernel 3: fused attention, softmax over HEADS (lane-local), barrier-free
// k-loop. grid 256 blocks = B * (Tq/16), 1 block/CU, XCD-swizzled.
// 512 threads = 8 waves; wave w owns k-strip [w*256, w*256+256).
//   S^T via mfma(K_frag, Q_frag): lane holds S[k=(lg*4+r)][q=lm] for 8 heads.
//   softmax over h: lane-local. Normalized weights land EXACTLY in the
//   B-fragment layout for the PV mfma -> no LDS roundtrip / barriers in-loop.
//   accO stays in VGPRs: ALL indexing is compile-time (epilogue fully
//   unrolled -- runtime head index would demote accO to scratch, rule #20).
// ---------------------------------------------------------------------------
__global__ __launch_bounds__(512, 2) void attn_kernel(
    const float* __restrict__ Q,
    const __hip_bfloat16* __restrict__ K,
    const __hip_bfloat16* __restrict__ Vt,
    float* __restrict__ Out) {
  // XCD swizzle: 256 blocks, 8 XCDs -> XCD x gets logical blocks [x*32, x*32+32)
  const int bx = blockIdx.x;
  const int L  = (bx & 7) * 32 + (bx >> 3);
  const int b  = L >> 7;
  const int q0 = (L & 127) << 4;
  const int tid = threadIdx.x;
  const int w  = tid >> 6;
  const int l  = tid & 63;
  const int lm = l & 15;
  const int lg = l >> 4;

  __shared__ __bf16 Qs[16 * 512];      // XOR-swizzled q-tile (16 rows x 1KB)
  __shared__ float  Obuf[8][64][17];   // [wave][d][q+pad] reduction buffer

  // ---- stage Q tile to LDS (bf16, swizzled) ----
  {
    const int row = tid >> 5;          // 0..15
    const int seg = tid & 31;          // 16 floats each
    const float* src = Q + ((size_t)(b * TSEQ + q0 + row)) * DMODEL + seg * 16;
    bf16x8 lo = cvt8(src);
    bf16x8 hi = cvt8(src + 8);
    char* base = (char*)Qs;
    const int sw = (row & 7) << 4;
    *(bf16x8*)(base + ((row * 1024 + seg * 32) ^ sw))      = lo;
    *(bf16x8*)(base + ((row * 1024 + seg * 32 + 16) ^ sw)) = hi;
  }
  __syncthreads();

  f32x4 accO[NHEAD][4];   // [h][dt], O^T: d = dt*16 + lg*4 + r, q = lm
  #pragma unroll
  for (int h = 0; h < NHEAD; ++h)
    #pragma unroll
    for (int j = 0; j < 4; ++j) accO[h][j] = (f32x4){0.f, 0.f, 0.f, 0.f};

  const float cl2 = 0.125f * 1.44269504f;   // dh^-0.5 * log2(e)
  const char* qb = (const char*)Qs;
  const int qsw = (lm & 7) << 4;

  for (int pr = 0; pr < 8; ++pr) {
    const int kset0 = w * 256 + pr * 32;
    bf16x8 wf[NHEAD];                  // normalized weights, B-frag layout

    #pragma unroll
    for (int s2 = 0; s2 < 2; ++s2) {
      const int kset = kset0 + s2 * 16;
      f32x4 sv[NHEAD];
      const __hip_bfloat16* kbase =
          K + ((size_t)(b * TSEQ + kset + lm)) * DMODEL + lg * 8;
      #pragma unroll
      for (int h = 0; h < NHEAD; ++h) {
        bf16x8 kf0 = load_b8(kbase + h * 64);
        bf16x8 kf1 = load_b8(kbase + h * 64 + 32);
        bf16x8 qf0 = *(const bf16x8*)(qb + ((lm * 1024 + h * 128 + lg * 16) ^ qsw));
        bf16x8 qf1 = *(const bf16x8*)(qb + ((lm * 1024 + h * 128 + 64 + lg * 16) ^ qsw));
        f32x4 t = {0.f, 0.f, 0.f, 0.f};
        t = __builtin_amdgcn_mfma_f32_16x16x32_bf16(kf0, qf0, t, 0, 0, 0);
        t = __builtin_amdgcn_mfma_f32_16x16x32_bf16(kf1, qf1, t, 0, 0, 0);
        sv[h] = t;
      }
      // softmax over heads (lane-local), per k-slot r
      #pragma unroll
      for (int r = 0; r < 4; ++r) {
        float v[NHEAD];
        #pragma unroll
        for (int h = 0; h < NHEAD; ++h) v[h] = sv[h][r] * cl2;
        float m = fmaxf(fmaxf(fmaxf(v[0], v[1]), fmaxf(v[2], v[3])),
                        fmaxf(fmaxf(v[4], v[5]), fmaxf(v[6], v[7])));
        float e[NHEAD];
        float sum = 0.f;
        #pragma unroll
        for (int h = 0; h < NHEAD; ++h) { e[h] = exp2f(v[h] - m); sum += e[h]; }
        const float inv = __builtin_amdgcn_rcpf(sum);
        #pragma unroll
        for (int h = 0; h < NHEAD; ++h)
          wf[h][s2 * 4 + r] = (__bf16)(e[h] * inv);
      }
    }

    // ---- PV: O^T[d][q] += sum_k V[k][d] * w[q][k], K=32 over the pair ----
    const __hip_bfloat16* vbase =
        Vt + ((size_t)(b * DHEAD + lm)) * TSEQ + kset0 + lg * 4;
    #pragma unroll
    for (int dt = 0; dt < 4; ++dt) {
      bf16x4 v0 = load_b4(vbase + (size_t)dt * 16 * TSEQ);
      bf16x4 v1 = load_b4(vbase + (size_t)dt * 16 * TSEQ + 16);
      bf16x8 vf;
      #pragma unroll
      for (int j = 0; j < 4; ++j) { vf[j] = v0[j]; vf[j + 4] = v1[j]; }
      #pragma unroll
      for (int h = 0; h < NHEAD; ++h)
        accO[h][dt] = __builtin_amdgcn_mfma_f32_16x16x32_bf16(vf, wf[h], accO[h][dt], 0, 0, 0);
    }
  }

  // ---- epilogue: reduce 8 k-strip waves via LDS, one head per round.
  //      FULLY UNROLLED so accO indexing stays compile-time (stays in VGPRs).
  #pragma unroll
  for (int h = 0; h < NHEAD; ++h) {
    #pragma unroll
    for (int dt = 0; dt < 4; ++dt)
      #pragma unroll
      for (int r = 0; r < 4; ++r)
        Obuf[w][dt * 16 + lg * 4 + r][lm] = accO[h][dt][r];
    __syncthreads();

    {
      const int q  = tid >> 5;         // 0..15
      const int d0 = (tid & 31) * 2;   // 2 d per thread
      float s0 = 0.f, s1 = 0.f;
      #pragma unroll
      for (int ww = 0; ww < 8; ++ww) {
        s0 += Obuf[ww][d0][q];
        s1 += Obuf[ww][d0 + 1][q];
      }
      float2* dst = reinterpret_cast<float2*>(
          &Out[((size_t)(b * TSEQ + q0 + q)) * DMODEL + h * DHEAD + d0]);
      *dst = float2{s0, s1};
    }
    __syncthreads();
  }
}

// ---------------------------------------------------------------------------
extern "C" void kernel_launch(void* const* d_in, const int* in_sizes, int n_in,
                              void* d_out, int out_size, void* d_ws, size_t ws_size,
                              hipStream_t stream) {
  const float* Q    = (const float*)d_in[0];
  const float* V    = (const float*)d_in[1];
  const float* W    = (const float*)d_in[2];
  const float* bias = (const float*)d_in[3];
  float* Out = (float*)d_out;

  // ws layout: K bf16 [2][2048][512] (4 MiB) | Vt bf16 [2][64][2048] (0.5 MiB)
  __hip_bfloat16* Kbuf = (__hip_bfloat16*)d_ws;
  __hip_bfloat16* Vt   = Kbuf + (size_t)BATCH * TSEQ * DMODEL;

  conv_kernel<<<256, 256, 0, stream>>>(V, W, bias, Kbuf);
  vt_kernel<<<64, 256, 0, stream>>>(V, Vt);
  attn_kernel<<<BATCH * (TSEQ / 16), 512, 0, stream>>>(Q, Kbuf, Vt, Out);
}

// Round 7
// 118.246 us; speedup vs baseline: 1.6410x; 1.0055x over previous
//
#include <hip/hip_runtime.h>
#include <hip/hip_bf16.h>

// Problem constants (fixed by the bench): B=2, Tq=Tv=2048, D=512, H=8, dh=64.
// Inputs and output are FLOAT32.
#define BATCH 2
#define TSEQ  2048
#define DMODEL 512
#define NHEAD 8
#define DHEAD 64

typedef __bf16 bf16x2 __attribute__((ext_vector_type(2)));
typedef __bf16 bf16x4 __attribute__((ext_vector_type(4)));
typedef __bf16 bf16x8 __attribute__((ext_vector_type(8)));
typedef float  f32x4  __attribute__((ext_vector_type(4)));

__device__ __forceinline__ bf16x8 load_b8(const void* p) {
  return __builtin_bit_cast(bf16x8, *reinterpret_cast<const uint4*>(p));
}
__device__ __forceinline__ bf16x4 load_b4(const void* p) {
  return __builtin_bit_cast(bf16x4, *reinterpret_cast<const uint2*>(p));
}

// load 8 fp32 and convert to bf16x8 (p must be 16B-aligned)
__device__ __forceinline__ bf16x8 cvt8(const float* p) {
  float4 a = *reinterpret_cast<const float4*>(p);
  float4 b = *reinterpret_cast<const float4*>(p + 4);
  bf16x8 r;
  r[0] = (__bf16)a.x; r[1] = (__bf16)a.y; r[2] = (__bf16)a.z; r[3] = (__bf16)a.w;
  r[4] = (__bf16)b.x; r[5] = (__bf16)b.y; r[6] = (__bf16)b.z; r[7] = (__bf16)b.w;
  return r;
}

// ---------------------------------------------------------------------------
// Kernel 1: K[b][t][o] = sum_d V[b][t][d] * W[o][d] + bias[o]   (conv1d, k=1)
// grid 256 blocks (B * Tv/16), 256 threads; wave w owns 8 of 32 o-tiles.
// ---------------------------------------------------------------------------
__global__ __launch_bounds__(256) void conv_kernel(
    const float* __restrict__ V,
    const float* __restrict__ W,
    const float* __restrict__ bias,
    __hip_bfloat16* __restrict__ K) {
  const int bx = blockIdx.x;
  const int b  = bx >> 7;
  const int t0 = (bx & 127) << 4;
  const int w  = threadIdx.x >> 6;
  const int l  = threadIdx.x & 63;
  const int lm = l & 15;
  const int lg = l >> 4;

  const float* vrow = V + ((size_t)(b * TSEQ + t0 + lm)) * DHEAD;
  bf16x8 av0 = cvt8(vrow + lg * 8);
  bf16x8 av1 = cvt8(vrow + 32 + lg * 8);

  #pragma unroll
  for (int n = 0; n < 8; ++n) {
    const int o0 = (w * 8 + n) * 16;
    const float* wrow = W + ((size_t)(o0 + lm)) * DHEAD;
    bf16x8 b0 = cvt8(wrow + lg * 8);
    bf16x8 b1 = cvt8(wrow + 32 + lg * 8);
    f32x4 acc = {0.f, 0.f, 0.f, 0.f};
    acc = __builtin_amdgcn_mfma_f32_16x16x32_bf16(av0, b0, acc, 0, 0, 0);
    acc = __builtin_amdgcn_mfma_f32_16x16x32_bf16(av1, b1, acc, 0, 0, 0);
    const float bv = bias[o0 + lm];
    #pragma unroll
    for (int r = 0; r < 4; ++r) {
      const int t = t0 + lg * 4 + r;
      K[((size_t)(b * TSEQ + t)) * DMODEL + o0 + lm] =
          __float2bfloat16(acc[r] + bv);
    }
  }
}

// ---------------------------------------------------------------------------
// Kernel 2: Vt[b][d][t] = (bf16) V[b][t][d] via LDS tile transpose.
// grid 64 blocks (B * Tv/64), 256 threads.
// ---------------------------------------------------------------------------
__global__ __launch_bounds__(256) void vt_kernel(const float* __restrict__ V,
                                                 __hip_bfloat16* __restrict__ Vt) {
  const int bx = blockIdx.x;
  const int b  = bx >> 5;
  const int t0 = (bx & 31) << 6;
  const int tid = threadIdx.x;
  __shared__ float tile[64][65];

  #pragma unroll
  for (int p = 0; p < 4; ++p) {
    const int r = p * 16 + (tid >> 4);
    const int c = (tid & 15) * 4;
    float4 v = *reinterpret_cast<const float4*>(
        &V[((size_t)(b * TSEQ + t0 + r)) * DHEAD + c]);
    tile[r][c]     = v.x;
    tile[r][c + 1] = v.y;
    tile[r][c + 2] = v.z;
    tile[r][c + 3] = v.w;
  }
  __syncthreads();

  const int d  = tid >> 2;
  const int ts = (tid & 3) * 16;
  uint u[8];
  #pragma unroll
  for (int j = 0; j < 8; ++j) {
    bf16x2 p2;
    p2[0] = (__bf16)tile[ts + 2 * j][d];
    p2[1] = (__bf16)tile[ts + 2 * j + 1][d];
    u[j] = __builtin_bit_cast(uint, p2);
  }
  uint4* dst = reinterpret_cast<uint4*>(
      Vt + ((size_t)(b * DHEAD + d)) * TSEQ + t0 + ts);
  dst[0] = uint4{u[0], u[1], u[2], u[3]};
  dst[1] = uint4{u[4], u[5], u[6], u[7]};
}

// ---------------------------------------------------------------------------
// Kernel 3: fused attention, softmax over HEADS (lane-local), barrier-free
// k-loop. grid 256 blocks = B * (Tq/16), 1 block/CU, XCD-swizzled.
// 512 threads = 8 waves; wave w owns k-strip [w*256, w*256+256).
//   S^T via mfma(K_frag, Q_frag): lane holds S[k=(lg*4+r)][q=lm] for 8 heads.
//   softmax over h: lane-local. Normalized weights land EXACTLY in the
//   B-fragment layout for the PV mfma -> no LDS roundtrip / barriers in-loop.
// REGISTER BUDGET (the round-5/6 lesson): working set is ~224 VGPR
// (accO 128 + wf 32 + sv 32 + transients). __launch_bounds__ 2nd arg=2 was
// applied as 2 blocks/CU -> 4 waves/SIMD -> 128-VGPR cap -> accO spilled to
// scratch (83-162 MB of HBM scratch traffic, VALUBusy 0.2%). Use min=1 so
// the cap is >=256, and keep the pr-loop rolled so pipelining can't
// re-inflate live ranges past the cap.
// ---------------------------------------------------------------------------
__global__ __launch_bounds__(512, 1) void attn_kernel(
    const float* __restrict__ Q,
    const __hip_bfloat16* __restrict__ K,
    const __hip_bfloat16* __restrict__ Vt,
    float* __restrict__ Out) {
  // XCD swizzle: 256 blocks, 8 XCDs -> XCD x gets logical blocks [x*32, x*32+32)
  const int bx = blockIdx.x;
  const int L  = (bx & 7) * 32 + (bx >> 3);
  const int b  = L >> 7;
  const int q0 = (L & 127) << 4;
  const int tid = threadIdx.x;
  const int w  = tid >> 6;
  const int l  = tid & 63;
  const int lm = l & 15;
  const int lg = l >> 4;

  __shared__ __bf16 Qs[16 * 512];      // XOR-swizzled q-tile (16 rows x 1KB)
  __shared__ float  Obuf[8][64][17];   // [wave][d][q+pad] reduction buffer

  // ---- stage Q tile to LDS (bf16, swizzled) ----
  {
    const int row = tid >> 5;          // 0..15
    const int seg = tid & 31;          // 16 floats each
    const float* src = Q + ((size_t)(b * TSEQ + q0 + row)) * DMODEL + seg * 16;
    bf16x8 lo = cvt8(src);
    bf16x8 hi = cvt8(src + 8);
    char* base = (char*)Qs;
    const int sw = (row & 7) << 4;
    *(bf16x8*)(base + ((row * 1024 + seg * 32) ^ sw))      = lo;
    *(bf16x8*)(base + ((row * 1024 + seg * 32 + 16) ^ sw)) = hi;
  }
  __syncthreads();

  f32x4 accO[NHEAD][4];   // [h][dt], O^T: d = dt*16 + lg*4 + r, q = lm
  #pragma unroll
  for (int h = 0; h < NHEAD; ++h)
    #pragma unroll
    for (int j = 0; j < 4; ++j) accO[h][j] = (f32x4){0.f, 0.f, 0.f, 0.f};

  const float cl2 = 0.125f * 1.44269504f;   // dh^-0.5 * log2(e)
  const char* qb = (const char*)Qs;
  const int qsw = (lm & 7) << 4;

  #pragma unroll 1
  for (int pr = 0; pr < 8; ++pr) {
    const int kset0 = w * 256 + pr * 32;
    bf16x8 wf[NHEAD];                  // normalized weights, B-frag layout

    #pragma unroll
    for (int s2 = 0; s2 < 2; ++s2) {
      const int kset = kset0 + s2 * 16;
      f32x4 sv[NHEAD];
      const __hip_bfloat16* kbase =
          K + ((size_t)(b * TSEQ + kset + lm)) * DMODEL + lg * 8;
      #pragma unroll
      for (int h = 0; h < NHEAD; ++h) {
        bf16x8 kf0 = load_b8(kbase + h * 64);
        bf16x8 kf1 = load_b8(kbase + h * 64 + 32);
        bf16x8 qf0 = *(const bf16x8*)(qb + ((lm * 1024 + h * 128 + lg * 16) ^ qsw));
        bf16x8 qf1 = *(const bf16x8*)(qb + ((lm * 1024 + h * 128 + 64 + lg * 16) ^ qsw));
        f32x4 t = {0.f, 0.f, 0.f, 0.f};
        t = __builtin_amdgcn_mfma_f32_16x16x32_bf16(kf0, qf0, t, 0, 0, 0);
        t = __builtin_amdgcn_mfma_f32_16x16x32_bf16(kf1, qf1, t, 0, 0, 0);
        sv[h] = t;
      }
      // softmax over heads (lane-local), per k-slot r
      #pragma unroll
      for (int r = 0; r < 4; ++r) {
        float v[NHEAD];
        #pragma unroll
        for (int h = 0; h < NHEAD; ++h) v[h] = sv[h][r] * cl2;
        float m = fmaxf(fmaxf(fmaxf(v[0], v[1]), fmaxf(v[2], v[3])),
                        fmaxf(fmaxf(v[4], v[5]), fmaxf(v[6], v[7])));
        float e[NHEAD];
        float sum = 0.f;
        #pragma unroll
        for (int h = 0; h < NHEAD; ++h) { e[h] = exp2f(v[h] - m); sum += e[h]; }
        const float inv = __builtin_amdgcn_rcpf(sum);
        #pragma unroll
        for (int h = 0; h < NHEAD; ++h)
          wf[h][s2 * 4 + r] = (__bf16)(e[h] * inv);
      }
    }

    // ---- PV: O^T[d][q] += sum_k V[k][d] * w[q][k], K=32 over the pair ----
    const __hip_bfloat16* vbase =
        Vt + ((size_t)(b * DHEAD + lm)) * TSEQ + kset0 + lg * 4;
    #pragma unroll
    for (int dt = 0; dt < 4; ++dt) {
      bf16x4 v0 = load_b4(vbase + (size_t)dt * 16 * TSEQ);
      bf16x4 v1 = load_b4(vbase + (size_t)dt * 16 * TSEQ + 16);
      bf16x8 vf;
      #pragma unroll
      for (int j = 0; j < 4; ++j) { vf[j] = v0[j]; vf[j + 4] = v1[j]; }
      #pragma unroll
      for (int h = 0; h < NHEAD; ++h)
        accO[h][dt] = __builtin_amdgcn_mfma_f32_16x16x32_bf16(vf, wf[h], accO[h][dt], 0, 0, 0);
    }
  }

  // ---- epilogue: reduce 8 k-strip waves via LDS, one head per round.
  //      FULLY UNROLLED so accO indexing stays compile-time (stays in VGPRs).
  #pragma unroll
  for (int h = 0; h < NHEAD; ++h) {
    #pragma unroll
    for (int dt = 0; dt < 4; ++dt)
      #pragma unroll
      for (int r = 0; r < 4; ++r)
        Obuf[w][dt * 16 + lg * 4 + r][lm] = accO[h][dt][r];
    __syncthreads();

    {
      const int q  = tid >> 5;         // 0..15
      const int d0 = (tid & 31) * 2;   // 2 d per thread
      float s0 = 0.f, s1 = 0.f;
      #pragma unroll
      for (int ww = 0; ww < 8; ++ww) {
        s0 += Obuf[ww][d0][q];
        s1 += Obuf[ww][d0 + 1][q];
      }
      float2* dst = reinterpret_cast<float2*>(
          &Out[((size_t)(b * TSEQ + q0 + q)) * DMODEL + h * DHEAD + d0]);
      *dst = float2{s0, s1};
    }
    __syncthreads();
  }
}

// ---------------------------------------------------------------------------
extern "C" void kernel_launch(void* const* d_in, const int* in_sizes, int n_in,
                              void* d_out, int out_size, void* d_ws, size_t ws_size,
                              hipStream_t stream) {
  const float* Q    = (const float*)d_in[0];
  const float* V    = (const float*)d_in[1];
  const float* W    = (const float*)d_in[2];
  const float* bias = (const float*)d_in[3];
  float* Out = (float*)d_out;

  // ws layout: K bf16 [2][2048][512] (4 MiB) | Vt bf16 [2][64][2048] (0.5 MiB)
  __hip_bfloat16* Kbuf = (__hip_bfloat16*)d_ws;
  __hip_bfloat16* Vt   = Kbuf + (size_t)BATCH * TSEQ * DMODEL;

  conv_kernel<<<256, 256, 0, stream>>>(V, W, bias, Kbuf);
  vt_kernel<<<64, 256, 0, stream>>>(V, Vt);
  attn_kernel<<<BATCH * (TSEQ / 16), 512, 0, stream>>>(Q, Kbuf, Vt, Out);
}